// Round 1
// baseline (545.726 us; speedup 1.0000x reference)
//
#include <hip/hip_runtime.h>
#include <math.h>

// Problem constants (from reference)
#define NH      32      // query heads
#define KVH     8       // kv heads
#define GRP     4       // NH / KVH
#define DH      128     // head dim
#define BS      16      // tokens per cache block
#define D_TOT   1024    // KVH * DH floats per cache row
#define MBPS    128     // max blocks per seq
#define SPLIT_TOK 256   // tokens per split-K chunk
#define NSPLIT  8       // 2048 / SPLIT_TOK
#define SCALE_F 0.08838834764831845f

// ---------------- Kernel 1: scatter new K/V into paged cache ----------------
__global__ void store_kv_kernel(const float* __restrict__ k,
                                const float* __restrict__ v,
                                float* __restrict__ kc,
                                float* __restrict__ vc,
                                const int* __restrict__ slot_mapping) {
    int b = blockIdx.x;          // batch
    int t = threadIdx.x;         // 0..255 ; 256 * float4 = 1024 floats
    int s = slot_mapping[b];
    if (s < 0) return;           // mode="drop"
    const float4* k4 = (const float4*)(k + (size_t)b * D_TOT);
    const float4* v4 = (const float4*)(v + (size_t)b * D_TOT);
    float4* kc4 = (float4*)(kc + (size_t)s * D_TOT);
    float4* vc4 = (float4*)(vc + (size_t)s * D_TOT);
    kc4[t] = k4[t];
    vc4[t] = v4[t];
}

// ---------------- Kernel 2: split-K flash-decode partials ----------------
// grid (KVH, B, NSPLIT), block 256 = 4 waves; wave w handles query head kvh*4+w.
// Per wave: 16 lanes per token (4 tokens in flight), online softmax in regs,
// O accumulator: lane holds output dims [2*lane, 2*lane+1].
// ws layout per (b,kvh,split,g): 128 floats O_hat + m + l  (stride 130).
__global__ __launch_bounds__(256) void attn_partial_kernel(
    const float* __restrict__ q,
    const float* __restrict__ kc,
    const float* __restrict__ vc,
    const int* __restrict__ block_tables,
    const int* __restrict__ ctx_lens,
    float* __restrict__ ws)
{
    const int kvh   = blockIdx.x;
    const int b     = blockIdx.y;
    const int split = blockIdx.z;
    const int ctx   = ctx_lens[b];
    const int start = split * SPLIT_TOK;
    if (start >= ctx) return;                      // uniform early-exit
    const int end = min(ctx, start + SPLIT_TOK);

    const int wave = threadIdx.x >> 6;             // 0..3 (GQA sub-head)
    const int lane = threadIdx.x & 63;
    const int h    = kvh * GRP + wave;             // global query head
    const int dseg = lane & 15;                    // 16 lanes cover DH=128
    const int tsub = lane >> 4;                    // 4 tokens per pass

    // q fragment for score phase: lane covers d = dseg*4..+3 and 64+dseg*4..+3
    const float* qh = q + ((size_t)b * NH + h) * DH;
    const float4 q0 = *(const float4*)(qh + dseg * 4);
    const float4 q1 = *(const float4*)(qh + 64 + dseg * 4);

    const int* bt = block_tables + b * MBPS;

    float  m = -INFINITY;
    float  l = 0.f;
    float2 acc = make_float2(0.f, 0.f);

    for (int t0 = start; t0 < end; t0 += 4) {
        // ---- scores for tokens t0..t0+3 ----
        int tok  = t0 + tsub;
        int tokc = min(tok, end - 1);              // clamp addr for tail
        int blk  = bt[tokc >> 4];
        const float* krow = kc + ((size_t)blk * BS + (tokc & 15)) * D_TOT + kvh * DH;
        float4 k0 = *(const float4*)(krow + dseg * 4);
        float4 k1 = *(const float4*)(krow + 64 + dseg * 4);
        float p = q0.x*k0.x + q0.y*k0.y + q0.z*k0.z + q0.w*k0.w
                + q1.x*k1.x + q1.y*k1.y + q1.z*k1.z + q1.w*k1.w;
        p += __shfl_xor(p, 1);
        p += __shfl_xor(p, 2);
        p += __shfl_xor(p, 4);
        p += __shfl_xor(p, 8);                     // full dot in all 16 lanes
        float s = p * SCALE_F;
        if (tok >= end) s = -INFINITY;             // mask tail tokens

        // broadcast the 4 scores to the whole wave
        float s0 = __shfl(s, 0);
        float s1 = __shfl(s, 16);
        float s2 = __shfl(s, 32);
        float s3 = __shfl(s, 48);

        // ---- online softmax update (wave-uniform arithmetic) ----
        float mnew = fmaxf(fmaxf(fmaxf(fmaxf(m, s0), s1), s2), s3);
        float alpha = __expf(m - mnew);            // m=-inf first pass -> 0
        float p0 = __expf(s0 - mnew);
        float p1 = __expf(s1 - mnew);
        float p2 = __expf(s2 - mnew);
        float p3 = __expf(s3 - mnew);
        l = l * alpha + (p0 + p1 + p2 + p3);
        acc.x *= alpha;
        acc.y *= alpha;

        // ---- PV accumulate: lane owns dims 2*lane, 2*lane+1 ----
        #pragma unroll
        for (int j = 0; j < 4; ++j) {
            int tc = min(t0 + j, end - 1);
            int blkj = bt[tc >> 4];                // wave-uniform -> s_load
            const float* vrow = vc + ((size_t)blkj * BS + (tc & 15)) * D_TOT + kvh * DH;
            float2 vv = *(const float2*)(vrow + 2 * lane);
            float pj = (j == 0) ? p0 : (j == 1) ? p1 : (j == 2) ? p2 : p3;
            acc.x += pj * vv.x;
            acc.y += pj * vv.y;
        }
        m = mnew;
    }

    // ---- write partial (unnormalized O_hat, m, l) ----
    float* o = ws + ((((size_t)b * KVH + kvh) * NSPLIT + split) * GRP + wave) * 130;
    *(float2*)(o + 2 * lane) = acc;
    if (lane == 0) { o[128] = m; o[129] = l; }
}

// ---------------- Kernel 3: combine split partials ----------------
__global__ void combine_kernel(const float* __restrict__ ws,
                               const int* __restrict__ ctx_lens,
                               float* __restrict__ out)
{
    int bh = blockIdx.x;          // 0..1023 = (b, h)
    int b  = bh >> 5;
    int h  = bh & 31;
    int kvh = h >> 2;
    int g   = h & 3;
    int d   = threadIdx.x;        // 0..127
    int ctx = ctx_lens[b];
    int nsp = (ctx + SPLIT_TOK - 1) / SPLIT_TOK;  // active splits (>=1)

    const float* base = ws + ((size_t)b * KVH + kvh) * NSPLIT * GRP * 130 + (size_t)g * 130;
    const int stride = GRP * 130;

    float M = -INFINITY;
    for (int i = 0; i < nsp; ++i)
        M = fmaxf(M, base[i * stride + 128]);

    float L = 0.f, O = 0.f;
    for (int i = 0; i < nsp; ++i) {
        const float* p = base + i * stride;
        float w = __expf(p[128] - M);
        L += p[129] * w;
        O += p[d] * w;
    }
    out[((size_t)b * NH + h) * DH + d] = O / L;
}

// ---------------- launcher ----------------
extern "C" void kernel_launch(void* const* d_in, const int* in_sizes, int n_in,
                              void* d_out, int out_size, void* d_ws, size_t ws_size,
                              hipStream_t stream) {
    const float* q  = (const float*)d_in[0];
    const float* k  = (const float*)d_in[1];
    const float* v  = (const float*)d_in[2];
    float* kc       = (float*)d_in[3];   // mutated in place; harness restores inputs
    float* vc       = (float*)d_in[4];
    const int* slot = (const int*)d_in[5];
    const int* bt   = (const int*)d_in[6];
    const int* cl   = (const int*)d_in[7];
    float* out      = (float*)d_out;
    float* ws       = (float*)d_ws;

    store_kv_kernel<<<32, 256, 0, stream>>>(k, v, kc, vc, slot);
    attn_partial_kernel<<<dim3(KVH, 32, NSPLIT), 256, 0, stream>>>(q, kc, vc, bt, cl, ws);
    combine_kernel<<<1024, 128, 0, stream>>>(ws, cl, out);
}

// Round 2
// 490.962 us; speedup vs baseline: 1.1115x; 1.1115x over previous
//
#include <hip/hip_runtime.h>
#include <math.h>

// Problem constants (from reference)
#define NH      32      // query heads
#define KVH     8       // kv heads
#define GRP     4       // NH / KVH
#define DH      128     // head dim
#define BS      16      // tokens per cache block
#define D_TOT   1024    // KVH * DH floats per cache row
#define MBPS    128     // max blocks per seq
#define MAX_CTX 2048
#define SCALE_F 0.08838834764831845f
#define PSTRIDE 136     // floats per partial record (128 O + m + l + pad, 16B aligned)

// ---------------- Kernel 1: scatter new K/V into paged cache ----------------
__global__ void store_kv_kernel(const float* __restrict__ k,
                                const float* __restrict__ v,
                                float* __restrict__ kc,
                                float* __restrict__ vc,
                                const int* __restrict__ slot_mapping) {
    int b = blockIdx.x;          // batch
    int t = threadIdx.x;         // 0..255 ; 256 * float4 = 1024 floats
    int s = slot_mapping[b];
    if (s < 0) return;           // mode="drop"
    const float4* k4 = (const float4*)(k + (size_t)b * D_TOT);
    const float4* v4 = (const float4*)(v + (size_t)b * D_TOT);
    float4* kc4 = (float4*)(kc + (size_t)s * D_TOT);
    float4* vc4 = (float4*)(vc + (size_t)s * D_TOT);
    kc4[t] = k4[t];
    vc4[t] = v4[t];
}

// ---------------- Kernel 2: split-K flash-decode partials ----------------
// grid (KVH, B, nsplit), block 256 = 4 waves; wave w = query head kvh*4+w.
// Lane layout: tsub = lane>>4 (token in pass), dseg = lane&15 (8 dims/lane).
// Group-local PV: each 16-lane group accumulates its own token's p*V into
// acc[8]; cross-group reduce once at the end. No score broadcasts.
__global__ __launch_bounds__(256, 6) void attn_partial_kernel(
    const float* __restrict__ q,
    const float* __restrict__ kc,
    const float* __restrict__ vc,
    const int* __restrict__ block_tables,
    const int* __restrict__ ctx_lens,
    float* __restrict__ ws,
    int split_tok, int nsplit)
{
    const int kvh   = blockIdx.x;
    const int b     = blockIdx.y;
    const int split = blockIdx.z;
    const int ctx   = ctx_lens[b];
    const int start = split * split_tok;
    if (start >= ctx) return;                      // uniform early-exit
    const int end = min(ctx, start + split_tok);

    const int wave = threadIdx.x >> 6;             // 0..3 (GQA sub-head)
    const int lane = threadIdx.x & 63;
    const int h    = kvh * GRP + wave;             // global query head
    const int tsub = lane >> 4;                    // token within pass
    const int dseg = lane & 15;                    // 16 lanes cover DH per token

    // q fragment: this lane's 8 contiguous dims
    const float* qh = q + ((size_t)b * NH + h) * DH;
    const float4 qa = *(const float4*)(qh + dseg * 8);
    const float4 qb = *(const float4*)(qh + dseg * 8 + 4);

    const int* bt = block_tables + b * MBPS;

    float m = -INFINITY;
    float l = 0.f;
    float acc[8];
    #pragma unroll
    for (int j = 0; j < 8; ++j) acc[j] = 0.f;

    const int cb0 = start >> 4;                    // first cache block
    const int cb1 = (end + 15) >> 4;               // one past last

    for (int cb = cb0; cb < cb1; ++cb) {
        const int blk = bt[cb];                    // wave-uniform -> s_load
        const float* kbase = kc + (size_t)blk * BS * D_TOT + kvh * DH;
        const float* vbase = vc + (size_t)blk * BS * D_TOT + kvh * DH;
        const int tbase = cb << 4;

        #pragma unroll 2
        for (int ps = 0; ps < 4; ++ps) {
            const int tok  = tbase + ps * 4 + tsub;
            const int rofs = (ps * 4 + tsub) * D_TOT + dseg * 8;
            // K and V issued together: one vmcnt batch per pass
            float4 ka = *(const float4*)(kbase + rofs);
            float4 kb = *(const float4*)(kbase + rofs + 4);
            float4 va = *(const float4*)(vbase + rofs);
            float4 vb = *(const float4*)(vbase + rofs + 4);

            float s = qa.x*ka.x + qa.y*ka.y + qa.z*ka.z + qa.w*ka.w
                    + qb.x*kb.x + qb.y*kb.y + qb.z*kb.z + qb.w*kb.w;
            s += __shfl_xor(s, 1);
            s += __shfl_xor(s, 2);
            s += __shfl_xor(s, 4);
            s += __shfl_xor(s, 8);                 // group dot complete
            s *= SCALE_F;
            if (tok >= end) s = -INFINITY;         // mask tail tokens

            // wave max of the 4 scores (cross-group)
            float pm = fmaxf(s, __shfl_xor(s, 16));
            pm = fmaxf(pm, __shfl_xor(pm, 32));

            if (pm > m) {                          // wave-uniform, rare
                float alpha = __expf(m - pm);      // first pass: exp(-inf)=0
                l *= alpha;
                #pragma unroll
                for (int j = 0; j < 8; ++j) acc[j] *= alpha;
                m = pm;
            }

            float p = __expf(s - m);               // masked -> 0
            float psum = p + __shfl_xor(p, 16);
            psum += __shfl_xor(psum, 32);
            l += psum;                             // wave-uniform

            acc[0] += p * va.x; acc[1] += p * va.y;
            acc[2] += p * va.z; acc[3] += p * va.w;
            acc[4] += p * vb.x; acc[5] += p * vb.y;
            acc[6] += p * vb.z; acc[7] += p * vb.w;
        }
    }

    // cross-group reduce of the per-token partial accumulators
    #pragma unroll
    for (int j = 0; j < 8; ++j) {
        acc[j] += __shfl_xor(acc[j], 16);
        acc[j] += __shfl_xor(acc[j], 32);
    }

    // ---- write partial (unnormalized O_hat, m, l) ----
    float* o = ws + ((((size_t)b * KVH + kvh) * nsplit + split) * GRP + wave) * PSTRIDE;
    if (tsub == 0) {                               // lanes 0..15 cover 128 dims
        *(float4*)(o + dseg * 8)     = make_float4(acc[0], acc[1], acc[2], acc[3]);
        *(float4*)(o + dseg * 8 + 4) = make_float4(acc[4], acc[5], acc[6], acc[7]);
        if (lane == 0) { o[128] = m; o[129] = l; }
    }
}

// ---------------- Kernel 3: combine split partials ----------------
__global__ void combine_kernel(const float* __restrict__ ws,
                               const int* __restrict__ ctx_lens,
                               float* __restrict__ out,
                               int split_tok, int nsplit)
{
    int bh = blockIdx.x;          // 0..1023 = (b, h)
    int b  = bh >> 5;
    int h  = bh & 31;
    int kvh = h >> 2;
    int g   = h & 3;
    int d   = threadIdx.x;        // 0..127
    int ctx = ctx_lens[b];
    int nsp = (ctx + split_tok - 1) / split_tok;   // active splits (>=1)

    const float* base = ws + (((size_t)b * KVH + kvh) * nsplit + 0) * GRP * PSTRIDE
                           + (size_t)g * PSTRIDE;
    const int stride = GRP * PSTRIDE;

    float M = -INFINITY;
    for (int i = 0; i < nsp; ++i)
        M = fmaxf(M, base[i * stride + 128]);

    float L = 0.f, O = 0.f;
    for (int i = 0; i < nsp; ++i) {
        const float* p = base + i * stride;
        float w = __expf(p[128] - M);
        L += p[129] * w;
        O += p[d] * w;
    }
    out[((size_t)b * NH + h) * DH + d] = O / L;
}

// ---------------- launcher ----------------
extern "C" void kernel_launch(void* const* d_in, const int* in_sizes, int n_in,
                              void* d_out, int out_size, void* d_ws, size_t ws_size,
                              hipStream_t stream) {
    const float* q  = (const float*)d_in[0];
    const float* k  = (const float*)d_in[1];
    const float* v  = (const float*)d_in[2];
    float* kc       = (float*)d_in[3];   // mutated in place; harness restores inputs
    float* vc       = (float*)d_in[4];
    const int* slot = (const int*)d_in[5];
    const int* bt   = (const int*)d_in[6];
    const int* cl   = (const int*)d_in[7];
    float* out      = (float*)d_out;
    float* ws       = (float*)d_ws;

    // pick split count by available workspace (deterministic across calls)
    const size_t per_split = (size_t)32 * KVH * GRP * PSTRIDE * sizeof(float);
    int nsplit;
    if      (ws_size >= per_split * 16) nsplit = 16;
    else if (ws_size >= per_split * 8)  nsplit = 8;
    else                                nsplit = 4;
    int split_tok = MAX_CTX / nsplit;

    store_kv_kernel<<<32, 256, 0, stream>>>(k, v, kc, vc, slot);
    attn_partial_kernel<<<dim3(KVH, 32, nsplit), 256, 0, stream>>>(
        q, kc, vc, bt, cl, ws, split_tok, nsplit);
    combine_kernel<<<1024, 128, 0, stream>>>(ws, cl, out, split_tok, nsplit);
}